// Round 9
// baseline (178.273 us; speedup 1.0000x reference)
//
#include <hip/hip_runtime.h>

typedef unsigned short u16;
typedef unsigned int u32;
typedef __attribute__((ext_vector_type(8))) short s16x8;   // 8 bf16 (4 VGPRs) MFMA A/B frag
typedef __attribute__((ext_vector_type(4))) short s16x4;   // 4 bf16 (2 VGPRs)
typedef __attribute__((ext_vector_type(4))) float f32x4;   // MFMA C/D frag

#define DIM    1024
#define NHEADS 16
#define HD     64
#define NSEQ   2048
#define QKVN   3072

__device__ __forceinline__ u16 f2bf(float f) {
  u32 u = __float_as_uint(f);
  u += 0x7FFF + ((u >> 16) & 1);   // RNE
  return (u16)(u >> 16);
}

// exp2 via the compiler-visible intrinsic (single v_exp_f32 WITH hazard padding).
__device__ __forceinline__ float vexp2(float x) {
#if __has_builtin(__builtin_amdgcn_exp2f)
  return __builtin_amdgcn_exp2f(x);
#else
  return __expf(x * 0.69314718055994531f);
#endif
}

// async global->LDS, 16B per lane. LDS dst = wave-uniform base + lane*16.
__device__ __forceinline__ void async16(const u16* g, u16* l) {
  __builtin_amdgcn_global_load_lds(
      (const __attribute__((address_space(1))) unsigned int*)g,
      (__attribute__((address_space(3))) unsigned int*)l, 16, 0, 0);
}

// ---------------------------------------------------------------- cast fp32 -> bf16
__global__ void cast_all(const float* __restrict__ x, const float* __restrict__ wq,
                         const float* __restrict__ wp, u16* __restrict__ xo,
                         u16* __restrict__ wqo, u16* __restrict__ wpo) {
  int i = blockIdx.x * 256 + threadIdx.x;        // 2,097,152 threads, 4 floats each
  const float4* src; u16* dst; int off;
  if (i < 1048576)      { src = (const float4*)x;  dst = xo;  off = i; }
  else if (i < 1835008) { src = (const float4*)wq; dst = wqo; off = i - 1048576; }
  else                  { src = (const float4*)wp; dst = wpo; off = i - 1835008; }
  float4 f = src[off];
  ushort4 o;
  o.x = f2bf(f.x); o.y = f2bf(f.y); o.z = f2bf(f.z); o.w = f2bf(f.w);
  ((ushort4*)dst)[off] = o;
}

// ---------------------------------------------------------------- GEMM  C = A * B^T
// EXACT round-4 GEMM (2-deep prefetch). 9-run ledger: all GEMM micro-variants
// (single-buffer / 2-deep / 3-deep counted vmcnt / XCD swizzle) within the
// ±7us cross-run noise on the non-attn split. Frozen.
template <bool FINAL>
__global__ __launch_bounds__(256, 3) void gemm_bt(
    const u16* __restrict__ A, const u16* __restrict__ Bw, u16* __restrict__ qkv,
    u16* __restrict__ vt, const float* __restrict__ bias, float* __restrict__ outp) {
  constexpr int K = 1024;
  constexpr int BM = FINAL ? 64 : 128;
  constexpr int MT = FINAL ? 64 : 32;
  constexpr int IT = FINAL ? 2 : 4;           // 16-row i-tiles per wave
  constexpr int ACALLS = BM / 16;             // wave-calls to stage A tile (1 KB each)
  constexpr int TCALLS = ACALLS + 8;
  constexpr int PW = TCALLS / 4;              // calls per wave
  const int bm = blockIdx.x % MT;
  const int bn = blockIdx.x / MT;
  const int tid = threadIdx.x;
  const int wave = tid >> 6, lane = tid & 63;
  const int q4 = lane >> 4, l15 = lane & 15;
  const int wm = wave >> 1, wn = wave & 1;
  const int m0 = bm * BM, n0 = bn * 128;

  __shared__ alignas(16) u16 lsA[2][BM * 32];
  __shared__ alignas(16) u16 lsB[2][128 * 32];

  f32x4 acc[IT][4];
#pragma unroll
  for (int i = 0; i < IT; i++)
#pragma unroll
    for (int j = 0; j < 4; j++) acc[i][j] = (f32x4){0.f, 0.f, 0.f, 0.f};

  auto stage = [&](int k0, int buf) {
#pragma unroll
    for (int j = 0; j < PW; ++j) {
      int t = wave * PW + j;
      if (t < ACALLS) {
        int lin = t * 64 + lane;
        int r = lin >> 2, c = lin & 3;         // 4 x 16B chunks per 32-elem row
        async16(A + (size_t)(m0 + r) * K + k0 + c * 8, lsA[buf] + t * 512);
      } else {
        int tb = t - ACALLS;
        int lin = tb * 64 + lane;
        int r = lin >> 2, c = lin & 3;
        async16(Bw + (size_t)(n0 + r) * K + k0 + c * 8, lsB[buf] + tb * 512);
      }
    }
  };

  stage(0, 0);

  for (int k0 = 0; k0 < K; k0 += 32) {
    const int buf = (k0 >> 5) & 1;
    __syncthreads();                           // stage(k0) landed; prev compute done
    if (k0 + 32 < K) stage(k0 + 32, buf ^ 1);  // prefetch next into other buffer
    s16x8 af[IT], bfr[4];
#pragma unroll
    for (int i = 0; i < IT; ++i)
      af[i] = *(const s16x8*)(lsA[buf] + (wm * (IT * 16) + i * 16 + l15) * 32 + q4 * 8);
#pragma unroll
    for (int j = 0; j < 4; ++j)
      bfr[j] = *(const s16x8*)(lsB[buf] + (wn * 64 + j * 16 + l15) * 32 + q4 * 8);
    __builtin_amdgcn_s_setprio(1);
#pragma unroll
    for (int i = 0; i < IT; ++i)
#pragma unroll
      for (int j = 0; j < 4; ++j)
        acc[i][j] = __builtin_amdgcn_mfma_f32_16x16x32_bf16(af[i], bfr[j], acc[i][j], 0, 0, 0);
    __builtin_amdgcn_s_setprio(0);
  }

  // epilogue: C/D layout col=lane&15, row=quad*4+reg
#pragma unroll
  for (int i = 0; i < IT; i++) {
#pragma unroll
    for (int j = 0; j < 4; j++) {
      int n = n0 + wn * 64 + j * 16 + l15;
      int mb = m0 + wm * (IT * 16) + i * 16 + q4 * 4;
      if (FINAL) {
#pragma unroll
        for (int r = 0; r < 4; r++)
          outp[(size_t)(mb + r) * DIM + n] = acc[i][j][r] + bias[n];
      } else if (n < 2048) {
#pragma unroll
        for (int r = 0; r < 4; r++)
          qkv[(size_t)(mb + r) * QKVN + n] = f2bf(acc[i][j][r]);
      } else {
        int b = mb >> 11, tok = mb & 2047;
        int h = (n >> 6) & 15, hd = n & 63;
        ushort4 pk;
        pk.x = f2bf(acc[i][j][0]); pk.y = f2bf(acc[i][j][1]);
        pk.z = f2bf(acc[i][j][2]); pk.w = f2bf(acc[i][j][3]);
        *(ushort4*)(vt + ((size_t)((b * NHEADS + h) * HD + hd)) * NSEQ + tok) = pk;
      }
    }
  }
}

// ---------------------------------------------------------------- flash attention
// Round-9: 8 waves/block (512 thr), 2 key-groups x 4 q-waves, 32 q-rows/wave.
// R8 counters showed attn ~75% latency-stall (MfmaUtil 25, VALUBusy 42, no pipe
// half-busy) at 2 waves/SIMD. This doubles waves/SIMD to 4 at CONSTANT block
// count (512) and CONSTANT per-block staging/LDS/barriers — avoiding R3's trap
// (smaller Q-tile per BLOCK doubled total staging; here Q-rows per WAVE halve
// but per-block geometry is untouched).
// VGPR economy for the (512,2) 128-reg cap: the 64-key tile is processed in two
// 32-key HALVES (kf/vf8 live range 32 regs instead of 64) -> live set ~110.
// Spill alarm = FETCH_SIZE >> 12.4MB (R1 lesson).
// PV keeps R8's verified x32 k-slot-permutation form.
__global__ __launch_bounds__(512, 2) void attn_kernel(const u16* __restrict__ qkv,
                                                      const u16* __restrict__ vt,
                                                      u16* __restrict__ aout) {
  const int blk = blockIdx.x;            // 512 = 16 qtiles * 32 bh (bh fast)
  const int bh = blk & 31, qt = blk >> 5;
  const int b = bh >> 4, h = bh & 15;
  const int tid = threadIdx.x;
  const int wave = tid >> 6, lane = tid & 63;
  const int g = wave >> 2, wq = wave & 3;      // key-group, q-position (0..3)
  const int q4 = lane >> 4, l15 = lane & 15;

  __shared__ alignas(16) u16 smem[32768];      // 64 KB, hand-partitioned
  u16* lsKb = smem + g * 2 * 4096;             // this group's two K buffers
  u16* lsVb = smem + 16384 + g * 2 * 4096;     // this group's two V buffers
  float* lsO = (float*)smem;                   // combine overlay: 64 cols x stride 132
  float* lsS = lsO + 64 * 132;                 // + 128 row-sums (total 34304 B < 64 KB)

  // Q frags (B-operand of S^T MFMA), pre-scaled by log2(e)/8
  const float QSCALE = 0.18033688011112042f;       // log2(e)/8
  s16x8 aq[2][2];
#pragma unroll
  for (int rt = 0; rt < 2; ++rt)
#pragma unroll
    for (int kc = 0; kc < 2; ++kc) {
      int row = b * NSEQ + qt * 128 + wq * 32 + rt * 16 + l15;
      uint4 d = *(const uint4*)(qkv + (size_t)row * QKVN + h * HD + kc * 32 + q4 * 8);
      u32 w[4] = {d.x, d.y, d.z, d.w};
      s16x8 f;
#pragma unroll
      for (int j = 0; j < 8; ++j) {
        u16 u = (u16)(w[j >> 1] >> ((j & 1) * 16));
        float v = __uint_as_float(((u32)u) << 16) * QSCALE;
        f[j] = (short)f2bf(v);
      }
      aq[rt][kc] = f;
    }

  f32x4 o[2][4];
  float lsum[2] = {0.f, 0.f};                      // per-lane: qrow = l15 (per rt)
#pragma unroll
  for (int rt = 0; rt < 2; ++rt)
#pragma unroll
    for (int ht = 0; ht < 4; ++ht) o[rt][ht] = (f32x4){0.f, 0.f, 0.f, 0.f};

  // stage tile ktl of this group's key-half into buffer buf.
  // 16 calls/group (8 K + 8 V) spread over the group's 4 waves: 4 calls each.
  auto stage = [&](int ktl, int buf) {
#pragma unroll
    for (int j = 0; j < 4; ++j) {
      int id = wq * 4 + j;                         // 0..15 within group
      int t = id & 7;
      int lin = t * 64 + lane;
      int r = lin >> 3, c = (lin & 7) ^ (r & 7);
      int key = g * 1024 + ktl * 64;
      if (id < 8)
        async16(qkv + (size_t)(b * NSEQ + key + r) * QKVN + DIM + h * HD + c * 8,
                lsKb + buf * 4096 + t * 512);
      else
        async16(vt + (size_t)(bh * HD + r) * NSEQ + key + c * 8,
                lsVb + buf * 4096 + t * 512);
    }
  };

  stage(0, 0);

  for (int kt = 0; kt < 16; ++kt) {
    const int buf = kt & 1;
    __syncthreads();                               // stage(kt) complete; prev compute done
    if (kt + 1 < 16) stage(kt + 1, buf ^ 1);       // async into other buffer
    const u16* lsK = lsKb + buf * 4096;
    const u16* lsV = lsVb + buf * 4096;

    // process the 64-key tile in two 32-key halves (VGPR economy)
#pragma unroll
    for (int hf = 0; hf < 2; ++hf) {
      s16x8 kf[2][2];                              // [kc][ctl]: A-frag K[key][hd]
#pragma unroll
      for (int kc = 0; kc < 2; ++kc)
#pragma unroll
        for (int ctl = 0; ctl < 2; ++ctl) {
          int r = (hf * 2 + ctl) * 16 + l15;
          int c = (kc * 4 + q4) ^ (r & 7);
          kf[kc][ctl] = *(const s16x8*)(lsK + r * 64 + c * 8);
        }
      // V B-frag in the x32 permuted slot order (R8): slots 0-3 = keys
      // 32hf+4q4+j, slots 4-7 = keys 32hf+16+4q4+j-4.
      s16x8 vf8[4];                                // [ht]
#pragma unroll
      for (int ht = 0; ht < 4; ++ht) {
        int row = ht * 16 + l15;                   // hd row in lsV
        int ch0 = hf * 4 + (q4 >> 1);
        int ch1 = ch0 + 2;
        union { s16x4 hh[2]; s16x8 v; } u;
        u.hh[0] = *(const s16x4*)(lsV + row * 64 + (ch0 ^ (row & 7)) * 8 + (q4 & 1) * 4);
        u.hh[1] = *(const s16x4*)(lsV + row * 64 + (ch1 ^ (row & 7)) * 8 + (q4 & 1) * 4);
        vf8[ht] = u.v;
      }

#pragma unroll
      for (int rt = 0; rt < 2; ++rt) {
        // S^T = K * Q^T : per ctl, 16 keys x 16 qrows
        f32x4 st[2];
#pragma unroll
        for (int ctl = 0; ctl < 2; ++ctl) st[ctl] = (f32x4){0.f, 0.f, 0.f, 0.f};
#pragma unroll
        for (int kc = 0; kc < 2; ++kc)
#pragma unroll
          for (int ctl = 0; ctl < 2; ++ctl)
            st[ctl] = __builtin_amdgcn_mfma_f32_16x16x32_bf16(kf[kc][ctl], aq[rt][kc], st[ctl], 0, 0, 0);

        // P = exp2(S^T), truncated to bf16 in-register, packed as the x32
        // A-frag; lsum accumulates the truncated values (normalizer == MFMA in)
        s16x8 pa8;
        {
          union { u32 w[4]; s16x8 v; } pk;
#pragma unroll
          for (int h2 = 0; h2 < 2; ++h2) {
            u32 u0 = __float_as_uint(vexp2(st[h2][0]));
            u32 u1 = __float_as_uint(vexp2(st[h2][1]));
            u32 u2 = __float_as_uint(vexp2(st[h2][2]));
            u32 u3 = __float_as_uint(vexp2(st[h2][3]));
            lsum[rt] += __uint_as_float(u0 & 0xffff0000u) + __uint_as_float(u1 & 0xffff0000u) +
                        __uint_as_float(u2 & 0xffff0000u) + __uint_as_float(u3 & 0xffff0000u);
            pk.w[h2 * 2 + 0] = (u0 >> 16) | (u1 & 0xffff0000u);
            pk.w[h2 * 2 + 1] = (u2 >> 16) | (u3 & 0xffff0000u);
          }
          pa8 = pk.v;
        }

        // O += P * V  (16x16x32, 32 keys; slot order matches vf8)
#pragma unroll
        for (int ht = 0; ht < 4; ++ht)
          o[rt][ht] = __builtin_amdgcn_mfma_f32_16x16x32_bf16(pa8, vf8[ht], o[rt][ht], 0, 0, 0);
      }
    }
  }

  // reduce lsum across the 4 q4 replicas (every lane then holds qrow=l15's sum)
#pragma unroll
  for (int rt = 0; rt < 2; ++rt) {
    lsum[rt] += __shfl_xor(lsum[rt], 16, 64);
    lsum[rt] += __shfl_xor(lsum[rt], 32, 64);
  }

  __syncthreads();                                 // all staging reads done; overlay LDS
  if (g == 1) {
    // publish group-1 partials: O fp32 (col-major, stride 132, b128) + lsums
#pragma unroll
    for (int rt = 0; rt < 2; ++rt) {
#pragma unroll
      for (int ht = 0; ht < 4; ++ht) {
        int addr = (ht * 16 + l15) * 132 + wq * 32 + rt * 16 + q4 * 4;
        *(float4*)(lsO + addr) = (float4){o[rt][ht][0], o[rt][ht][1], o[rt][ht][2], o[rt][ht][3]};
      }
      if (q4 == 0) lsS[wq * 32 + rt * 16 + l15] = lsum[rt];
    }
  }
  __syncthreads();
  if (g == 0) {
#pragma unroll
    for (int rt = 0; rt < 2; ++rt) {
      float4 s2 = *(const float4*)(lsS + wq * 32 + rt * 16 + q4 * 4);  // broadcast
      float inv[4];
      inv[0] = 1.0f / (__shfl(lsum[rt], q4 * 4 + 0, 64) + s2.x);
      inv[1] = 1.0f / (__shfl(lsum[rt], q4 * 4 + 1, 64) + s2.y);
      inv[2] = 1.0f / (__shfl(lsum[rt], q4 * 4 + 2, 64) + s2.z);
      inv[3] = 1.0f / (__shfl(lsum[rt], q4 * 4 + 3, 64) + s2.w);
#pragma unroll
      for (int ht = 0; ht < 4; ++ht) {
        float4 o2 = *(const float4*)(lsO + (ht * 16 + l15) * 132 + wq * 32 + rt * 16 + q4 * 4);
        float v[4] = {o[rt][ht][0] + o2.x, o[rt][ht][1] + o2.y,
                      o[rt][ht][2] + o2.z, o[rt][ht][3] + o2.w};
#pragma unroll
        for (int r = 0; r < 4; ++r) {
          int n = qt * 128 + wq * 32 + rt * 16 + q4 * 4 + r;
          int col = h * HD + ht * 16 + l15;
          aout[(size_t)(b * NSEQ + n) * DIM + col] = f2bf(v[r] * inv[r]);
        }
      }
    }
  }
}

// ---------------------------------------------------------------- launch
extern "C" void kernel_launch(void* const* d_in, const int* in_sizes, int n_in,
                              void* d_out, int out_size, void* d_ws, size_t ws_size,
                              hipStream_t stream) {
  const float* x     = (const float*)d_in[0];
  const float* w_qkv = (const float*)d_in[1];
  const float* w_prj = (const float*)d_in[2];
  const float* b_prj = (const float*)d_in[3];
  float* out = (float*)d_out;

  char* ws = (char*)d_ws;
  u16* x_bf    = (u16*)(ws);                          // 8 MB
  u16* wqkv_bf = (u16*)(ws + (size_t)(8u << 20));     // 6 MB
  u16* wprj_bf = (u16*)(ws + (size_t)(14u << 20));    // 2 MB
  u16* qkv     = (u16*)(ws + (size_t)(16u << 20));    // 24 MB (Q,K used; V slot unused)
  u16* vt      = (u16*)(ws + (size_t)(40u << 20));    // 8 MB
  u16* aout    = (u16*)(ws + (size_t)(48u << 20));    // 8 MB   total 56 MB

  cast_all<<<8192, 256, 0, stream>>>(x, w_qkv, w_prj, x_bf, wqkv_bf, wprj_bf);
  gemm_bt<false><<<32 * 24, 256, 0, stream>>>(x_bf, wqkv_bf, qkv, vt, nullptr, nullptr);
  attn_kernel<<<512, 512, 0, stream>>>(qkv, vt, aout);
  gemm_bt<true><<<64 * 8, 256, 0, stream>>>(aout, wprj_bf, nullptr, nullptr, b_prj, out);
}

// Round 10
// 171.838 us; speedup vs baseline: 1.0374x; 1.0374x over previous
//
#include <hip/hip_runtime.h>

typedef unsigned short u16;
typedef unsigned int u32;
typedef __attribute__((ext_vector_type(8))) short s16x8;   // 8 bf16 (4 VGPRs) MFMA A/B frag
typedef __attribute__((ext_vector_type(4))) short s16x4;   // 4 bf16 (2 VGPRs)
typedef __attribute__((ext_vector_type(4))) float f32x4;   // MFMA C/D frag

#define DIM    1024
#define NHEADS 16
#define HD     64
#define NSEQ   2048
#define QKVN   3072

__device__ __forceinline__ u16 f2bf(float f) {
  u32 u = __float_as_uint(f);
  u += 0x7FFF + ((u >> 16) & 1);   // RNE
  return (u16)(u >> 16);
}

// exp2 via the compiler-visible intrinsic (single v_exp_f32 WITH hazard padding).
__device__ __forceinline__ float vexp2(float x) {
#if __has_builtin(__builtin_amdgcn_exp2f)
  return __builtin_amdgcn_exp2f(x);
#else
  return __expf(x * 0.69314718055994531f);
#endif
}

// async global->LDS, 16B per lane. LDS dst = wave-uniform base + lane*16.
__device__ __forceinline__ void async16(const u16* g, u16* l) {
  __builtin_amdgcn_global_load_lds(
      (const __attribute__((address_space(1))) unsigned int*)g,
      (__attribute__((address_space(3))) unsigned int*)l, 16, 0, 0);
}

// ---------------------------------------------------------------- cast fp32 -> bf16
__global__ void cast_all(const float* __restrict__ x, const float* __restrict__ wq,
                         const float* __restrict__ wp, u16* __restrict__ xo,
                         u16* __restrict__ wqo, u16* __restrict__ wpo) {
  int i = blockIdx.x * 256 + threadIdx.x;        // 2,097,152 threads, 4 floats each
  const float4* src; u16* dst; int off;
  if (i < 1048576)      { src = (const float4*)x;  dst = xo;  off = i; }
  else if (i < 1835008) { src = (const float4*)wq; dst = wqo; off = i - 1048576; }
  else                  { src = (const float4*)wp; dst = wpo; off = i - 1835008; }
  float4 f = src[off];
  ushort4 o;
  o.x = f2bf(f.x); o.y = f2bf(f.y); o.z = f2bf(f.z); o.w = f2bf(f.w);
  ((ushort4*)dst)[off] = o;
}

// ---------------------------------------------------------------- GEMM  C = A * B^T
// EXACT round-4 GEMM (2-deep prefetch). 10-run ledger: all GEMM micro-variants
// within the env+noise floor. Frozen.
template <bool FINAL>
__global__ __launch_bounds__(256, 3) void gemm_bt(
    const u16* __restrict__ A, const u16* __restrict__ Bw, u16* __restrict__ qkv,
    u16* __restrict__ vt, const float* __restrict__ bias, float* __restrict__ outp) {
  constexpr int K = 1024;
  constexpr int BM = FINAL ? 64 : 128;
  constexpr int MT = FINAL ? 64 : 32;
  constexpr int IT = FINAL ? 2 : 4;           // 16-row i-tiles per wave
  constexpr int ACALLS = BM / 16;             // wave-calls to stage A tile (1 KB each)
  constexpr int TCALLS = ACALLS + 8;
  constexpr int PW = TCALLS / 4;              // calls per wave
  const int bm = blockIdx.x % MT;
  const int bn = blockIdx.x / MT;
  const int tid = threadIdx.x;
  const int wave = tid >> 6, lane = tid & 63;
  const int q4 = lane >> 4, l15 = lane & 15;
  const int wm = wave >> 1, wn = wave & 1;
  const int m0 = bm * BM, n0 = bn * 128;

  __shared__ alignas(16) u16 lsA[2][BM * 32];
  __shared__ alignas(16) u16 lsB[2][128 * 32];

  f32x4 acc[IT][4];
#pragma unroll
  for (int i = 0; i < IT; i++)
#pragma unroll
    for (int j = 0; j < 4; j++) acc[i][j] = (f32x4){0.f, 0.f, 0.f, 0.f};

  auto stage = [&](int k0, int buf) {
#pragma unroll
    for (int j = 0; j < PW; ++j) {
      int t = wave * PW + j;
      if (t < ACALLS) {
        int lin = t * 64 + lane;
        int r = lin >> 2, c = lin & 3;         // 4 x 16B chunks per 32-elem row
        async16(A + (size_t)(m0 + r) * K + k0 + c * 8, lsA[buf] + t * 512);
      } else {
        int tb = t - ACALLS;
        int lin = tb * 64 + lane;
        int r = lin >> 2, c = lin & 3;
        async16(Bw + (size_t)(n0 + r) * K + k0 + c * 8, lsB[buf] + tb * 512);
      }
    }
  };

  stage(0, 0);

  for (int k0 = 0; k0 < K; k0 += 32) {
    const int buf = (k0 >> 5) & 1;
    __syncthreads();                           // stage(k0) landed; prev compute done
    if (k0 + 32 < K) stage(k0 + 32, buf ^ 1);  // prefetch next into other buffer
    s16x8 af[IT], bfr[4];
#pragma unroll
    for (int i = 0; i < IT; ++i)
      af[i] = *(const s16x8*)(lsA[buf] + (wm * (IT * 16) + i * 16 + l15) * 32 + q4 * 8);
#pragma unroll
    for (int j = 0; j < 4; ++j)
      bfr[j] = *(const s16x8*)(lsB[buf] + (wn * 64 + j * 16 + l15) * 32 + q4 * 8);
    __builtin_amdgcn_s_setprio(1);
#pragma unroll
    for (int i = 0; i < IT; ++i)
#pragma unroll
      for (int j = 0; j < 4; ++j)
        acc[i][j] = __builtin_amdgcn_mfma_f32_16x16x32_bf16(af[i], bfr[j], acc[i][j], 0, 0, 0);
    __builtin_amdgcn_s_setprio(0);
  }

  // epilogue: C/D layout col=lane&15, row=quad*4+reg
#pragma unroll
  for (int i = 0; i < IT; i++) {
#pragma unroll
    for (int j = 0; j < 4; j++) {
      int n = n0 + wn * 64 + j * 16 + l15;
      int mb = m0 + wm * (IT * 16) + i * 16 + q4 * 4;
      if (FINAL) {
#pragma unroll
        for (int r = 0; r < 4; r++)
          outp[(size_t)(mb + r) * DIM + n] = acc[i][j][r] + bias[n];
      } else if (n < 2048) {
#pragma unroll
        for (int r = 0; r < 4; r++)
          qkv[(size_t)(mb + r) * QKVN + n] = f2bf(acc[i][j][r]);
      } else {
        int b = mb >> 11, tok = mb & 2047;
        int h = (n >> 6) & 15, hd = n & 63;
        ushort4 pk;
        pk.x = f2bf(acc[i][j][0]); pk.y = f2bf(acc[i][j][1]);
        pk.z = f2bf(acc[i][j][2]); pk.w = f2bf(acc[i][j][3]);
        *(ushort4*)(vt + ((size_t)((b * NHEADS + h) * HD + hd)) * NSEQ + tok) = pk;
      }
    }
  }
}

// ---------------------------------------------------------------- flash attention
// Round-10: R8 base (4 waves, 128 q-rows, x32-permuted PV — best total 176.0)
// + two stacked changes whose tradeoffs FLIPPED after R8 halved PV MFMAs:
// 1) osum on the matrix pipe: rowsum(P) via mfma_x32(pa8, ones). At R8's
//    MfmaUtil=25% the MFMA pipe has idle headroom while VALU (42%) is the
//    busiest pipe — deletes the lsum mask+add chain (~128 VALU/wave*kt) and
//    the shfl_xor reduce for +8 MFMA/wave*kt (+12.5% on an idle pipe).
//    osum numerics verified in R4 (passed; env-corrected ledger: NEUTRAL at
//    x16, not a regression — R4-vs-R0 was env-confounded).
// 2) T5 s_setprio around MFMA clusters (+4-7% measured on attn, m191).
// R9 reverted: 8 waves/block doubled bank conflicts (2.16M->4.26M), MfmaUtil
// fell, no occupancy payoff.
// Env model: env A attn=51/non-attn~129; env B attn=60.5/non-attn~118.
__global__ __launch_bounds__(256, 2) void attn_kernel(const u16* __restrict__ qkv,
                                                      const u16* __restrict__ vt,
                                                      u16* __restrict__ aout) {
  const int blk = blockIdx.x;            // 512 = 16 qtiles * 32 bh (bh fast)
  const int bh = blk & 31, qt = blk >> 5;
  const int b = bh >> 4, h = bh & 15;
  const int tid = threadIdx.x;
  const int wave = tid >> 6, lane = tid & 63;
  const int g = wave >> 1, wq = wave & 1;      // key-group, q-position
  const int q4 = lane >> 4, l15 = lane & 15;

  __shared__ alignas(16) u16 smem[32768];      // 64 KB, hand-partitioned
  u16* lsKb = smem + g * 2 * 4096;             // this group's two K buffers
  u16* lsVb = smem + 16384 + g * 2 * 4096;     // this group's two V buffers
  float* lsO = (float*)smem;                   // combine overlay: 64 cols x stride 132
  float* lsS = lsO + 64 * 132;                 // + 128 row-sums (total 34304 B < 64 KB)

  // Q frags (B-operand of S^T MFMA), pre-scaled by log2(e)/8
  const float QSCALE = 0.18033688011112042f;       // log2(e)/8
  s16x8 aq[4][2];
#pragma unroll
  for (int rt = 0; rt < 4; ++rt)
#pragma unroll
    for (int kc = 0; kc < 2; ++kc) {
      int row = b * NSEQ + qt * 128 + wq * 64 + rt * 16 + l15;
      uint4 d = *(const uint4*)(qkv + (size_t)row * QKVN + h * HD + kc * 32 + q4 * 8);
      u32 w[4] = {d.x, d.y, d.z, d.w};
      s16x8 f;
#pragma unroll
      for (int j = 0; j < 8; ++j) {
        u16 u = (u16)(w[j >> 1] >> ((j & 1) * 16));
        float v = __uint_as_float(((u32)u) << 16) * QSCALE;
        f[j] = (short)f2bf(v);
      }
      aq[rt][kc] = f;
    }

  f32x4 o[4][4];
  f32x4 osum[4];                                   // rowsum(P): row = q4*4+r, dup over l15
  const s16x8 vones8 = {(short)0x3F80, (short)0x3F80, (short)0x3F80, (short)0x3F80,
                        (short)0x3F80, (short)0x3F80, (short)0x3F80, (short)0x3F80};
#pragma unroll
  for (int rt = 0; rt < 4; ++rt) {
    osum[rt] = (f32x4){0.f, 0.f, 0.f, 0.f};
#pragma unroll
    for (int ht = 0; ht < 4; ++ht) o[rt][ht] = (f32x4){0.f, 0.f, 0.f, 0.f};
  }

  // stage tile ktl of this group's key-half into buffer buf (8 K + 8 V calls / 2 waves)
  auto stage = [&](int ktl, int buf) {
#pragma unroll
    for (int j = 0; j < 4; ++j) {
      int t = wq * 4 + j;                          // 0..7
      int lin = t * 64 + lane;
      int r = lin >> 3, c = (lin & 7) ^ (r & 7);
      int key = g * 1024 + ktl * 64;
      async16(qkv + (size_t)(b * NSEQ + key + r) * QKVN + DIM + h * HD + c * 8,
              lsKb + buf * 4096 + t * 512);
      async16(vt + (size_t)(bh * HD + r) * NSEQ + key + c * 8,
              lsVb + buf * 4096 + t * 512);
    }
  };

  stage(0, 0);

  for (int kt = 0; kt < 16; ++kt) {
    const int buf = kt & 1;
    __syncthreads();                               // stage(kt) complete; prev compute done
    if (kt + 1 < 16) stage(kt + 1, buf ^ 1);       // async into other buffer
    const u16* lsK = lsKb + buf * 4096;
    const u16* lsV = lsVb + buf * 4096;

    // hoisted fragment loads (shared by all 4 rt chains)
    s16x8 kf[2][4];                                // [kc][ct]: A-frag K[key][hd]
#pragma unroll
    for (int kc = 0; kc < 2; ++kc)
#pragma unroll
      for (int ct = 0; ct < 4; ++ct) {
        int r = ct * 16 + l15;
        int c = (kc * 4 + q4) ^ (r & 7);
        kf[kc][ct] = *(const s16x8*)(lsK + r * 64 + c * 8);
      }
    // V B-frags in PERMUTED slot order matching pa8 (R8 layout):
    // slot j<4 = keys 32c+4q4+j, slot j>=4 = keys 32c+16+4q4+j-4.
    s16x8 vf8[2][4];                               // [c(32-key chunk)][ht]
#pragma unroll
    for (int c = 0; c < 2; ++c)
#pragma unroll
      for (int ht = 0; ht < 4; ++ht) {
        int row = ht * 16 + l15;                   // hd row in lsV
        int ch0 = c * 4 + (q4 >> 1);               // 16B chunk of keys 32c+4q4..
        int ch1 = ch0 + 2;                         // 16B chunk of keys 32c+16+4q4..
        union { s16x4 hh[2]; s16x8 v; } u;
        u.hh[0] = *(const s16x4*)(lsV + row * 64 + (ch0 ^ (row & 7)) * 8 + (q4 & 1) * 4);
        u.hh[1] = *(const s16x4*)(lsV + row * 64 + (ch1 ^ (row & 7)) * 8 + (q4 & 1) * 4);
        vf8[c][ht] = u.v;
      }

#pragma unroll
    for (int rt = 0; rt < 4; ++rt) {
      // S^T = K * Q^T : per ct, 16 keys x 16 qrows
      f32x4 st[4];
#pragma unroll
      for (int ct = 0; ct < 4; ++ct) st[ct] = (f32x4){0.f, 0.f, 0.f, 0.f};
      __builtin_amdgcn_s_setprio(1);
#pragma unroll
      for (int kc = 0; kc < 2; ++kc)
#pragma unroll
        for (int ct = 0; ct < 4; ++ct)
          st[ct] = __builtin_amdgcn_mfma_f32_16x16x32_bf16(kf[kc][ct], aq[rt][kc], st[ct], 0, 0, 0);
      __builtin_amdgcn_s_setprio(0);

      // P = exp2(S^T), truncated to bf16 in-register, packed directly as the
      // x32 A-frag (w[0..1] = ct=2c, w[2..3] = ct=2c+1)
      s16x8 pa8[2];
#pragma unroll
      for (int c = 0; c < 2; ++c) {
        union { u32 w[4]; s16x8 v; } pk;
#pragma unroll
        for (int h2 = 0; h2 < 2; ++h2) {
          int ct = c * 2 + h2;
          u32 u0 = __float_as_uint(vexp2(st[ct][0]));
          u32 u1 = __float_as_uint(vexp2(st[ct][1]));
          u32 u2 = __float_as_uint(vexp2(st[ct][2]));
          u32 u3 = __float_as_uint(vexp2(st[ct][3]));
          pk.w[h2 * 2 + 0] = (u0 >> 16) | (u1 & 0xffff0000u);
          pk.w[h2 * 2 + 1] = (u2 >> 16) | (u3 & 0xffff0000u);
        }
        pa8[c] = pk.v;
      }

      // O += P * V (16x16x32); rowsum(P) on the matrix pipe (normalizer ==
      // exact MFMA input: same truncated bf16 addends, fp32 accumulation)
      __builtin_amdgcn_s_setprio(1);
#pragma unroll
      for (int c = 0; c < 2; ++c) {
        osum[rt] = __builtin_amdgcn_mfma_f32_16x16x32_bf16(pa8[c], vones8, osum[rt], 0, 0, 0);
#pragma unroll
        for (int ht = 0; ht < 4; ++ht)
          o[rt][ht] = __builtin_amdgcn_mfma_f32_16x16x32_bf16(pa8[c], vf8[c][ht], o[rt][ht], 0, 0, 0);
      }
      __builtin_amdgcn_s_setprio(0);
    }
  }

  __syncthreads();                                 // all staging reads done; overlay LDS
  if (g == 1) {
    // publish group-1 partials: O fp32 (col-major, stride 132, b128) + row-sums
#pragma unroll
    for (int rt = 0; rt < 4; ++rt) {
#pragma unroll
      for (int ht = 0; ht < 4; ++ht) {
        int addr = (ht * 16 + l15) * 132 + wq * 64 + rt * 16 + q4 * 4;
        *(float4*)(lsO + addr) = (float4){o[rt][ht][0], o[rt][ht][1], o[rt][ht][2], o[rt][ht][3]};
      }
      if (l15 == 0) {
#pragma unroll
        for (int r = 0; r < 4; ++r)
          lsS[wq * 64 + rt * 16 + q4 * 4 + r] = osum[rt][r];
      }
    }
  }
  __syncthreads();
  if (g == 0) {
#pragma unroll
    for (int rt = 0; rt < 4; ++rt) {
      float4 s2 = *(const float4*)(lsS + wq * 64 + rt * 16 + q4 * 4);  // broadcast
      float inv[4];
      inv[0] = 1.0f / (osum[rt][0] + s2.x);
      inv[1] = 1.0f / (osum[rt][1] + s2.y);
      inv[2] = 1.0f / (osum[rt][2] + s2.z);
      inv[3] = 1.0f / (osum[rt][3] + s2.w);
#pragma unroll
      for (int ht = 0; ht < 4; ++ht) {
        float4 o2 = *(const float4*)(lsO + (ht * 16 + l15) * 132 + wq * 64 + rt * 16 + q4 * 4);
        float v[4] = {o[rt][ht][0] + o2.x, o[rt][ht][1] + o2.y,
                      o[rt][ht][2] + o2.z, o[rt][ht][3] + o2.w};
#pragma unroll
        for (int r = 0; r < 4; ++r) {
          int n = qt * 128 + wq * 64 + rt * 16 + q4 * 4 + r;
          int col = h * HD + ht * 16 + l15;
          aout[(size_t)(b * NSEQ + n) * DIM + col] = f2bf(v[r] * inv[r]);
        }
      }
    }
  }
}

// ---------------------------------------------------------------- launch
extern "C" void kernel_launch(void* const* d_in, const int* in_sizes, int n_in,
                              void* d_out, int out_size, void* d_ws, size_t ws_size,
                              hipStream_t stream) {
  const float* x     = (const float*)d_in[0];
  const float* w_qkv = (const float*)d_in[1];
  const float* w_prj = (const float*)d_in[2];
  const float* b_prj = (const float*)d_in[3];
  float* out = (float*)d_out;

  char* ws = (char*)d_ws;
  u16* x_bf    = (u16*)(ws);                          // 8 MB
  u16* wqkv_bf = (u16*)(ws + (size_t)(8u << 20));     // 6 MB
  u16* wprj_bf = (u16*)(ws + (size_t)(14u << 20));    // 2 MB
  u16* qkv     = (u16*)(ws + (size_t)(16u << 20));    // 24 MB (Q,K used; V slot unused)
  u16* vt      = (u16*)(ws + (size_t)(40u << 20));    // 8 MB
  u16* aout    = (u16*)(ws + (size_t)(48u << 20));    // 8 MB   total 56 MB

  cast_all<<<8192, 256, 0, stream>>>(x, w_qkv, w_prj, x_bf, wqkv_bf, wprj_bf);
  gemm_bt<false><<<32 * 24, 256, 0, stream>>>(x_bf, wqkv_bf, qkv, vt, nullptr, nullptr);
  attn_kernel<<<512, 256, 0, stream>>>(qkv, vt, aout);
  gemm_bt<true><<<64 * 8, 256, 0, stream>>>(aout, wprj_bf, nullptr, nullptr, b_prj, out);
}